// Round 3
// baseline (394.139 us; speedup 1.0000x reference)
//
#include <hip/hip_runtime.h>

// GRU: H=32, I=1, B=2048, T=1024, fused output Linear(32,1).
// v15 = v14's structure (1 batch/wave, K split across the two 32-lane
// halves, 2048 waves = 2 waves/SIMD for stall overlap) with the recurrent
// matmul in PURE F32 (v14's f16 re-split failed absmax 1.37e-2 > 8e-3:
// the f16 path had no precision margin left for a summation-order change).
//  * per half: 3 v_fma + 45 v_fmac (f32) -- same 48 weight VGPRs as the
//    packed-f16 version, h in v36-v51 (16 f32)
//  * h publish is now a bare ds_write_b32 (no cvt on the critical chain);
//    h-half reads are 4x ds_read_b128 same-address broadcast (free)
//  * cross-half combine: mov + v_permlane32_swap + add per gate
//    (semantics-independent: copy, half-swap, add = lo+hi in all lanes)
//  * biases folded into kh=0 partials; TAIL (exp-based sigmoid/tanh, f32)
//    replicated per half; y stash stride 33; half 0 stores y and h_n

constexpr int H  = 32;
constexpr int TT = 1024;
constexpr int BB = 2048;

// 48 f32 FMA block: accumulates partial r,z,n for this lane's K-half from
// h-regs v36-v51 (16 f32)
#define DOT48F                                         \
    "v_fma_f32 v68, %[r0], v36, %[br]\n\t"             \
    "v_fma_f32 v69, %[z0], v36, %[bz]\n\t"             \
    "v_fma_f32 v70, %[n0], v36, %[bn]\n\t"             \
    "v_fmac_f32 v68, %[r1], v37\n\t"                   \
    "v_fmac_f32 v69, %[z1], v37\n\t"                   \
    "v_fmac_f32 v70, %[n1], v37\n\t"                   \
    "v_fmac_f32 v68, %[r2], v38\n\t"                   \
    "v_fmac_f32 v69, %[z2], v38\n\t"                   \
    "v_fmac_f32 v70, %[n2], v38\n\t"                   \
    "v_fmac_f32 v68, %[r3], v39\n\t"                   \
    "v_fmac_f32 v69, %[z3], v39\n\t"                   \
    "v_fmac_f32 v70, %[n3], v39\n\t"                   \
    "v_fmac_f32 v68, %[r4], v40\n\t"                   \
    "v_fmac_f32 v69, %[z4], v40\n\t"                   \
    "v_fmac_f32 v70, %[n4], v40\n\t"                   \
    "v_fmac_f32 v68, %[r5], v41\n\t"                   \
    "v_fmac_f32 v69, %[z5], v41\n\t"                   \
    "v_fmac_f32 v70, %[n5], v41\n\t"                   \
    "v_fmac_f32 v68, %[r6], v42\n\t"                   \
    "v_fmac_f32 v69, %[z6], v42\n\t"                   \
    "v_fmac_f32 v70, %[n6], v42\n\t"                   \
    "v_fmac_f32 v68, %[r7], v43\n\t"                   \
    "v_fmac_f32 v69, %[z7], v43\n\t"                   \
    "v_fmac_f32 v70, %[n7], v43\n\t"                   \
    "v_fmac_f32 v68, %[r8], v44\n\t"                   \
    "v_fmac_f32 v69, %[z8], v44\n\t"                   \
    "v_fmac_f32 v70, %[n8], v44\n\t"                   \
    "v_fmac_f32 v68, %[r9], v45\n\t"                   \
    "v_fmac_f32 v69, %[z9], v45\n\t"                   \
    "v_fmac_f32 v70, %[n9], v45\n\t"                   \
    "v_fmac_f32 v68, %[r10], v46\n\t"                  \
    "v_fmac_f32 v69, %[z10], v46\n\t"                  \
    "v_fmac_f32 v70, %[n10], v46\n\t"                  \
    "v_fmac_f32 v68, %[r11], v47\n\t"                  \
    "v_fmac_f32 v69, %[z11], v47\n\t"                  \
    "v_fmac_f32 v70, %[n11], v47\n\t"                  \
    "v_fmac_f32 v68, %[r12], v48\n\t"                  \
    "v_fmac_f32 v69, %[z12], v48\n\t"                  \
    "v_fmac_f32 v70, %[n12], v48\n\t"                  \
    "v_fmac_f32 v68, %[r13], v49\n\t"                  \
    "v_fmac_f32 v69, %[z13], v49\n\t"                  \
    "v_fmac_f32 v70, %[n13], v49\n\t"                  \
    "v_fmac_f32 v68, %[r14], v50\n\t"                  \
    "v_fmac_f32 v69, %[z14], v50\n\t"                  \
    "v_fmac_f32 v70, %[n14], v50\n\t"                  \
    "v_fmac_f32 v68, %[r15], v51\n\t"                  \
    "v_fmac_f32 v69, %[z15], v51\n\t"                  \
    "v_fmac_f32 v70, %[n15], v51\n\t"

// cross-half reduce: after this v68/v69/v70 hold full r,z,n pre-acts in
// ALL 64 lanes. Correct under either v_permlane32_swap half-swap semantic:
// q=copy(p); halfswap(q,p) leaves {q,p} = {lo-bcast,hi-bcast} in some
// order; q+p = lo+hi everywhere.
#define COMBINE                                        \
    "v_mov_b32 v64, v68\n\t"                           \
    "v_mov_b32 v65, v69\n\t"                           \
    "v_mov_b32 v66, v70\n\t"                           \
    "s_nop 1\n\t"                                      \
    "v_permlane32_swap_b32 v64, v68\n\t"               \
    "v_permlane32_swap_b32 v65, v69\n\t"               \
    "v_permlane32_swap_b32 v66, v70\n\t"               \
    "s_nop 1\n\t"                                      \
    "v_add_f32 v68, v64, v68\n\t"                      \
    "v_add_f32 v69, v65, v69\n\t"                      \
    "v_add_f32 v70, v66, v70\n\t"

// gate tail: XREG = x register for this step, HREG = h register (updated)
#define TAIL(XREG, HREG)                               \
    "v_fmac_f32 v68, " XREG ", %[wir]\n\t"             \
    "v_fmac_f32 v69, " XREG ", %[wiz]\n\t"             \
    "v_exp_f32 v71, v68\n\t"                           \
    "v_exp_f32 v72, v69\n\t"                           \
    "v_fma_f32 v74, " XREG ", %[wi], %[bi]\n\t"        \
    "s_nop 3\n\t"                                      \
    "v_add_f32 v71, 1.0, v71\n\t"                      \
    "v_add_f32 v72, 1.0, v72\n\t"                      \
    "v_rcp_f32 v71, v71\n\t"                           \
    "v_rcp_f32 v72, v72\n\t"                           \
    "s_nop 3\n\t"                                      \
    "v_fmac_f32 v74, v71, v70\n\t"                     \
    "v_exp_f32 v75, v74\n\t"                           \
    "s_nop 3\n\t"                                      \
    "v_add_f32 v75, 1.0, v75\n\t"                      \
    "v_rcp_f32 v75, v75\n\t"                           \
    "s_nop 3\n\t"                                      \
    "v_fma_f32 v76, -2.0, v75, 1.0\n\t"                \
    "v_sub_f32 v77, " HREG ", v76\n\t"                 \
    "v_fma_f32 " HREG ", v72, v77, v76\n\t"

__global__ __launch_bounds__(256, 2)
void gru_fused(const float* __restrict__ x,      // [B,T]
               const float* __restrict__ h0,     // [1,B,H]
               const float* __restrict__ W_ih,   // [3H,1]
               const float* __restrict__ W_hh,   // [3H,H]
               const float* __restrict__ b_ih,   // [3H]
               const float* __restrict__ b_hh,   // [3H]
               const float* __restrict__ W_out,  // [1,H]
               const float* __restrict__ b_out,  // [1]
               float* __restrict__ out)          // y[B,T] ++ h_n[B,H]
{
    __shared__ __align__(64) float hbuf[4][2][32];   // [wave][kh][j]
    __shared__ __align__(8) float xstage[4][2][36];  // [wave][kh][step] (+pad)
    __shared__ float ybuf[4][2][33 * 32];            // [wave][kh][33*s + j]

    const int tid  = threadIdx.x;
    const int w    = tid >> 6;
    const int lane = tid & 63;
    const int half = lane >> 5;     // K-half this lane accumulates
    const int j    = lane & 31;     // output unit
    const int b    = (blockIdx.x << 2) | w;   // one batch per wave

    const float NL2E = -1.44269504f;
    const float P2L2 =  2.88539008f;

    const float* Wrp = &W_hh[(0 * H + j) * H];
    const float* Wzp = &W_hh[(1 * H + j) * H];
    const float* Wnp = &W_hh[(2 * H + j) * H];
    const int kb = 16 * half;
    float wr[16], wz[16], wn[16];
#pragma unroll
    for (int p = 0; p < 16; ++p) {
        wr[p] = Wrp[kb + p] * NL2E;
        wz[p] = Wzp[kb + p] * NL2E;
        wn[p] = Wnp[kb + p] * P2L2;
    }
    // biases folded into the kh=0 partial only (combine adds halves)
    const float br  = half ? 0.0f : (b_ih[j] + b_hh[j]) * NL2E;
    const float bz  = half ? 0.0f : (b_ih[H + j] + b_hh[H + j]) * NL2E;
    const float bhn = half ? 0.0f : b_hh[2 * H + j] * P2L2;
    // tail constants: applied once per lane on the combined pre-acts
    const float wir = W_ih[j] * NL2E;
    const float wiz = W_ih[H + j] * NL2E;
    const float win = W_ih[2 * H + j] * P2L2;
    const float bin = b_ih[2 * H + j] * P2L2;
    const float wo  = W_out[j];
    const float bo  = b_out[0];

    float h = h0[b * H + j];        // replicated across halves

    const float* xb = x + (size_t)b * TT;
    float*       yb = out + (size_t)b * TT;

    const unsigned ha = (unsigned)(size_t)&hbuf[w][half][j];         // publish
    const unsigned hr = (unsigned)(size_t)&hbuf[w][half][16 * half]; // 4xb128
    const unsigned xw = (unsigned)(size_t)&xstage[w][half][j];       // stage
    const unsigned xa = (unsigned)(size_t)&xstage[w][half][0];       // b64 reads
    const unsigned ya = (unsigned)(size_t)&ybuf[w][half][j];         // y stash
    const float* yr = &ybuf[w][half][0];

#pragma unroll 1
    for (int t0 = 0; t0 < TT; t0 += 32) {
        const float xv = xb[t0 + j];   // halves load/stage identical copies

        asm volatile(
            "s_mov_b32 s20, 16\n\t"
            "v_mov_b32 v82, %[ya]\n\t"
            "v_mov_b32 v83, %[xa]\n\t"
            // prologue: LDS queue = [xstage, xrd, pub, r0-r3, ywrDummy] (8)
            "ds_write_b32 %[xw], %[xv]\n\t"
            "ds_read_b64 v[80:81], v83\n\t"            // x_0, x_1
            "ds_write_b32 %[ha], %[h]\n\t"
            "ds_read_b128 v[36:39], %[hr]\n\t"
            "ds_read_b128 v[40:43], %[hr] offset:16\n\t"
            "ds_read_b128 v[44:47], %[hr] offset:32\n\t"
            "ds_read_b128 v[48:51], %[hr] offset:48\n\t"
            "ds_write_b32 v82, v78\n\t"                // dummy y (overwritten)

            "L_gru_%=:\n\t"
            // ---------- step A (even) ----------
            "s_waitcnt lgkmcnt(1)\n\t"                 // h-reads + x landed
            DOT48F
            COMBINE
            TAIL("v80", "%[h]")
            // publish + reads for step B, then y-write A
            "ds_write_b32 %[ha], %[h]\n\t"
            "ds_read_b128 v[36:39], %[hr]\n\t"
            "ds_read_b128 v[40:43], %[hr] offset:16\n\t"
            "ds_read_b128 v[44:47], %[hr] offset:32\n\t"
            "ds_read_b128 v[48:51], %[hr] offset:48\n\t"
            "v_mul_f32 v78, %[wo], %[h]\n\t"
            "ds_write_b32 v82, v78\n\t"                // ywrA
            // ---------- step B (odd) ----------
            "s_waitcnt lgkmcnt(1)\n\t"                 // B's reads landed
            DOT48F
            COMBINE
            TAIL("v81", "%[h]")
            // publish + reads for next iter's step A; prefetch next x pair
            "ds_write_b32 %[ha], %[h]\n\t"
            "ds_read_b128 v[36:39], %[hr]\n\t"
            "ds_read_b128 v[40:43], %[hr] offset:16\n\t"
            "ds_read_b128 v[44:47], %[hr] offset:32\n\t"
            "ds_read_b128 v[48:51], %[hr] offset:48\n\t"
            "ds_read_b64 v[80:81], v83 offset:8\n\t"   // x_{s+2}, x_{s+3}
            "v_mul_f32 v78, %[wo], %[h]\n\t"
            "ds_write_b32 v82, v78 offset:132\n\t"     // ywrB
            // bookkeeping
            "v_add_u32 v82, 264, v82\n\t"
            "v_add_u32 v83, 8, v83\n\t"
            "s_sub_i32 s20, s20, 1\n\t"
            "s_cmp_gt_i32 s20, 0\n\t"
            "s_cbranch_scc1 L_gru_%=\n\t"
            "s_waitcnt lgkmcnt(0)"
            : [h]"+v"(h)
            : [xv]"v"(xv), [ha]"v"(ha), [hr]"v"(hr), [xw]"v"(xw), [xa]"v"(xa),
              [ya]"v"(ya),
              [wir]"v"(wir), [wiz]"v"(wiz), [wi]"v"(win), [bi]"v"(bin),
              [wo]"v"(wo), [br]"v"(br), [bz]"v"(bz), [bn]"v"(bhn),
              [r0]"v"(wr[0]), [r1]"v"(wr[1]), [r2]"v"(wr[2]), [r3]"v"(wr[3]),
              [r4]"v"(wr[4]), [r5]"v"(wr[5]), [r6]"v"(wr[6]), [r7]"v"(wr[7]),
              [r8]"v"(wr[8]), [r9]"v"(wr[9]), [r10]"v"(wr[10]), [r11]"v"(wr[11]),
              [r12]"v"(wr[12]), [r13]"v"(wr[13]), [r14]"v"(wr[14]), [r15]"v"(wr[15]),
              [z0]"v"(wz[0]), [z1]"v"(wz[1]), [z2]"v"(wz[2]), [z3]"v"(wz[3]),
              [z4]"v"(wz[4]), [z5]"v"(wz[5]), [z6]"v"(wz[6]), [z7]"v"(wz[7]),
              [z8]"v"(wz[8]), [z9]"v"(wz[9]), [z10]"v"(wz[10]), [z11]"v"(wz[11]),
              [z12]"v"(wz[12]), [z13]"v"(wz[13]), [z14]"v"(wz[14]), [z15]"v"(wz[15]),
              [n0]"v"(wn[0]), [n1]"v"(wn[1]), [n2]"v"(wn[2]), [n3]"v"(wn[3]),
              [n4]"v"(wn[4]), [n5]"v"(wn[5]), [n6]"v"(wn[6]), [n7]"v"(wn[7]),
              [n8]"v"(wn[8]), [n9]"v"(wn[9]), [n10]"v"(wn[10]), [n11]"v"(wn[11]),
              [n12]"v"(wn[12]), [n13]"v"(wn[13]), [n14]"v"(wn[14]), [n15]"v"(wn[15])
            : "memory", "scc", "s20",
              "v36", "v37", "v38", "v39", "v40", "v41", "v42", "v43",
              "v44", "v45", "v46", "v47", "v48", "v49", "v50", "v51",
              "v64", "v65", "v66",
              "v68", "v69", "v70", "v71", "v72", "v74", "v75", "v76", "v77",
              "v78", "v80", "v81", "v82", "v83");

        // amortized y reduction: stride 33 (conflict-free across j);
        // both halves compute (identical), only half 0 stores
        float s0 = 0.0f, s1 = 0.0f, s2 = 0.0f, s3 = 0.0f;
#pragma unroll
        for (int k = 0; k < 32; k += 4) {
            s0 += yr[33 * j + k + 0];
            s1 += yr[33 * j + k + 1];
            s2 += yr[33 * j + k + 2];
            s3 += yr[33 * j + k + 3];
        }
        if (!half) yb[t0 + j] = (s0 + s1) + (s2 + s3) + bo;
        __builtin_amdgcn_wave_barrier();
    }

    if (!half) out[(size_t)BB * TT + b * H + j] = h;

#undef DOT48F
#undef COMBINE
#undef TAIL
}

extern "C" void kernel_launch(void* const* d_in, const int* in_sizes, int n_in,
                              void* d_out, int out_size, void* d_ws, size_t ws_size,
                              hipStream_t stream) {
    const float* x     = (const float*)d_in[0];
    const float* h0    = (const float*)d_in[1];
    const float* W_ih  = (const float*)d_in[2];
    const float* W_hh  = (const float*)d_in[3];
    const float* b_ih  = (const float*)d_in[4];
    const float* b_hh  = (const float*)d_in[5];
    const float* W_out = (const float*)d_in[6];
    const float* b_out = (const float*)d_in[7];
    float* out = (float*)d_out;

    dim3 grid(BB / 4);   // 512 blocks: 4 waves x 1 batch each = 2048 waves
    dim3 block(256);     // 2 blocks/CU -> 2 waves/SIMD
    gru_fused<<<grid, block, 0, stream>>>(x, h0, W_ih, W_hh, b_ih, b_hh,
                                          W_out, b_out, out);
}

// Round 4
// 288.142 us; speedup vs baseline: 1.3679x; 1.3679x over previous
//
#include <hip/hip_runtime.h>

// GRU: H=32, I=1, B=2048, T=1024, fused output Linear(32,1).
// v16 = v12 (half-wave per batch, full K per lane, 1024 waves = 1/SIMD,
// f16 weights + dot2 -- the issue-floor layout) + stall surgery, with
// BIT-IDENTICAL float sequencing to v12 (v14's lesson: no reorder):
//  * graded lgkmcnt waits: DOT48 split into 4x12 keyed on the 4
//    ds_read_b128 returns, waits (4),(3),(2),(1) -- dots start on the
//    FIRST read's return, not the last's (DS completes in-order/wave)
//  * TAIL_B trans-shadow fills: x-prefetch ds_read_b64, v83 bump,
//    s_sub/s_cmp moved into the s_nop3 slots (spacing preserved >=4cy);
//    x-read now precedes pubB so wait grading is uniform for both steps
//  * v13 (DPP butterfly) and v14/v15 (K-split across halves) both
//    regressed: DPP hazard-interlock cost > LDS RT; K-split duplicates
//    TAIL+COMBINE issue > stall hidden by 2 waves/SIMD.

constexpr int H  = 32;
constexpr int TT = 1024;
constexpr int BB = 2048;

typedef _Float16 hf2 __attribute__((ext_vector_type(2)));

__device__ __forceinline__ unsigned pack2(float a, float b) {
    hf2 t; t.x = (_Float16)a; t.y = (_Float16)b;
    return __builtin_bit_cast(unsigned, t);
}

// DOT48 split into 4 groups of 12, each keyed on one ds_read_b128
#define DOT12_0                                        \
    "v_dot2_f32_f16 v68, %[r0], v36, %[br]\n\t"        \
    "v_dot2_f32_f16 v69, %[z0], v36, %[bz]\n\t"        \
    "v_dot2_f32_f16 v70, %[n0], v36, %[bn]\n\t"        \
    "v_dot2_f32_f16 v68, %[r1], v37, v68\n\t"          \
    "v_dot2_f32_f16 v69, %[z1], v37, v69\n\t"          \
    "v_dot2_f32_f16 v70, %[n1], v37, v70\n\t"          \
    "v_dot2_f32_f16 v68, %[r2], v38, v68\n\t"          \
    "v_dot2_f32_f16 v69, %[z2], v38, v69\n\t"          \
    "v_dot2_f32_f16 v70, %[n2], v38, v70\n\t"          \
    "v_dot2_f32_f16 v68, %[r3], v39, v68\n\t"          \
    "v_dot2_f32_f16 v69, %[z3], v39, v69\n\t"          \
    "v_dot2_f32_f16 v70, %[n3], v39, v70\n\t"

#define DOT12_1                                        \
    "v_dot2_f32_f16 v68, %[r4], v40, v68\n\t"          \
    "v_dot2_f32_f16 v69, %[z4], v40, v69\n\t"          \
    "v_dot2_f32_f16 v70, %[n4], v40, v70\n\t"          \
    "v_dot2_f32_f16 v68, %[r5], v41, v68\n\t"          \
    "v_dot2_f32_f16 v69, %[z5], v41, v69\n\t"          \
    "v_dot2_f32_f16 v70, %[n5], v41, v70\n\t"          \
    "v_dot2_f32_f16 v68, %[r6], v42, v68\n\t"          \
    "v_dot2_f32_f16 v69, %[z6], v42, v69\n\t"          \
    "v_dot2_f32_f16 v70, %[n6], v42, v70\n\t"          \
    "v_dot2_f32_f16 v68, %[r7], v43, v68\n\t"          \
    "v_dot2_f32_f16 v69, %[z7], v43, v69\n\t"          \
    "v_dot2_f32_f16 v70, %[n7], v43, v70\n\t"

#define DOT12_2                                        \
    "v_dot2_f32_f16 v68, %[r8], v44, v68\n\t"          \
    "v_dot2_f32_f16 v69, %[z8], v44, v69\n\t"          \
    "v_dot2_f32_f16 v70, %[n8], v44, v70\n\t"          \
    "v_dot2_f32_f16 v68, %[r9], v45, v68\n\t"          \
    "v_dot2_f32_f16 v69, %[z9], v45, v69\n\t"          \
    "v_dot2_f32_f16 v70, %[n9], v45, v70\n\t"          \
    "v_dot2_f32_f16 v68, %[r10], v46, v68\n\t"         \
    "v_dot2_f32_f16 v69, %[z10], v46, v69\n\t"         \
    "v_dot2_f32_f16 v70, %[n10], v46, v70\n\t"         \
    "v_dot2_f32_f16 v68, %[r11], v47, v68\n\t"         \
    "v_dot2_f32_f16 v69, %[z11], v47, v69\n\t"         \
    "v_dot2_f32_f16 v70, %[n11], v47, v70\n\t"

#define DOT12_3                                        \
    "v_dot2_f32_f16 v68, %[r12], v48, v68\n\t"         \
    "v_dot2_f32_f16 v69, %[z12], v48, v69\n\t"         \
    "v_dot2_f32_f16 v70, %[n12], v48, v70\n\t"         \
    "v_dot2_f32_f16 v68, %[r13], v49, v68\n\t"         \
    "v_dot2_f32_f16 v69, %[z13], v49, v69\n\t"         \
    "v_dot2_f32_f16 v70, %[n13], v49, v70\n\t"         \
    "v_dot2_f32_f16 v68, %[r14], v50, v68\n\t"         \
    "v_dot2_f32_f16 v69, %[z14], v50, v69\n\t"         \
    "v_dot2_f32_f16 v70, %[n14], v50, v70\n\t"         \
    "v_dot2_f32_f16 v68, %[r15], v51, v68\n\t"         \
    "v_dot2_f32_f16 v69, %[z15], v51, v69\n\t"         \
    "v_dot2_f32_f16 v70, %[n15], v51, v70\n\t"

// graded-wait DOT: dots start as soon as their b128 lands (in-order DS)
#define DOT48G                                         \
    "s_waitcnt lgkmcnt(4)\n\t"                         \
    DOT12_0                                            \
    "s_waitcnt lgkmcnt(3)\n\t"                         \
    DOT12_1                                            \
    "s_waitcnt lgkmcnt(2)\n\t"                         \
    DOT12_2                                            \
    "s_waitcnt lgkmcnt(1)\n\t"                         \
    DOT12_3

// gate tail, step A: unchanged from v12 (pure s_nop shadows)
#define TAILA                                          \
    "v_fmac_f32 v68, v80, %[wir]\n\t"                  \
    "v_fmac_f32 v69, v80, %[wiz]\n\t"                  \
    "v_exp_f32 v71, v68\n\t"                           \
    "v_exp_f32 v72, v69\n\t"                           \
    "v_fma_f32 v74, v80, %[wi], %[bi]\n\t"             \
    "s_nop 3\n\t"                                      \
    "v_add_f32 v71, 1.0, v71\n\t"                      \
    "v_add_f32 v72, 1.0, v72\n\t"                      \
    "v_rcp_f32 v71, v71\n\t"                           \
    "v_rcp_f32 v72, v72\n\t"                           \
    "s_nop 3\n\t"                                      \
    "v_fmac_f32 v74, v71, v70\n\t"                     \
    "v_exp_f32 v75, v74\n\t"                           \
    "s_nop 3\n\t"                                      \
    "v_add_f32 v75, 1.0, v75\n\t"                      \
    "v_rcp_f32 v75, v75\n\t"                           \
    "s_nop 3\n\t"                                      \
    "v_fma_f32 v76, -2.0, v75, 1.0\n\t"                \
    "v_sub_f32 v77, %[h], v76\n\t"                     \
    "v_fma_f32 %[h], v72, v77, v76\n\t"

// gate tail, step B: trans shadows filled with independent work
// (x-prefetch, v83 bump, loop counter); float sequence identical to TAILA.
// v81 (x_B) dead after the v74 fma, so the ds_read_b64 overwrite is safe;
// the x-read issuing BEFORE pubB keeps next step's wait grading uniform.
#define TAILB                                          \
    "v_fmac_f32 v68, v81, %[wir]\n\t"                  \
    "v_fmac_f32 v69, v81, %[wiz]\n\t"                  \
    "v_exp_f32 v71, v68\n\t"                           \
    "v_exp_f32 v72, v69\n\t"                           \
    "v_fma_f32 v74, v81, %[wi], %[bi]\n\t"             \
    "v_add_u32 v83, 8, v83\n\t"                        \
    "s_nop 1\n\t"                                      \
    "v_add_f32 v71, 1.0, v71\n\t"                      \
    "v_add_f32 v72, 1.0, v72\n\t"                      \
    "v_rcp_f32 v71, v71\n\t"                           \
    "v_rcp_f32 v72, v72\n\t"                           \
    "ds_read_b64 v[80:81], v83\n\t"                    \
    "s_nop 1\n\t"                                      \
    "v_fmac_f32 v74, v71, v70\n\t"                     \
    "v_exp_f32 v75, v74\n\t"                           \
    "s_nop 3\n\t"                                      \
    "v_add_f32 v75, 1.0, v75\n\t"                      \
    "v_rcp_f32 v75, v75\n\t"                           \
    "s_sub_i32 s20, s20, 1\n\t"                        \
    "s_cmp_gt_i32 s20, 0\n\t"                          \
    "s_nop 1\n\t"                                      \
    "v_fma_f32 v76, -2.0, v75, 1.0\n\t"                \
    "v_sub_f32 v77, %[h], v76\n\t"                     \
    "v_fma_f32 %[h], v72, v77, v76\n\t"

__global__ __launch_bounds__(256, 1)
void gru_fused(const float* __restrict__ x,      // [B,T]
               const float* __restrict__ h0,     // [1,B,H]
               const float* __restrict__ W_ih,   // [3H,1]
               const float* __restrict__ W_hh,   // [3H,H]
               const float* __restrict__ b_ih,   // [3H]
               const float* __restrict__ b_hh,   // [3H]
               const float* __restrict__ W_out,  // [1,H]
               const float* __restrict__ b_out,  // [1]
               float* __restrict__ out)          // y[B,T] ++ h_n[B,H]
{
    __shared__ __align__(16) _Float16 hbuf[4][64];   // [wave][half*32+unit]
    __shared__ __align__(8) float xstage[4][2][36];  // [wave][half][step] (+pad)
    __shared__ float ybuf[4][2][33 * 32];            // [wave][half][33*s + j]

    const int tid  = threadIdx.x;
    const int w    = tid >> 6;
    const int lane = tid & 63;
    const int half = lane >> 5;
    const int j    = lane & 31;
    const int gw   = (blockIdx.x << 2) | w;   // 0..1023
    const int b    = (gw << 1) | half;        // this lane's batch

    const float NL2E = -1.44269504f;
    const float P2L2 =  2.88539008f;

    const float* Wrp = &W_hh[(0 * H + j) * H];
    const float* Wzp = &W_hh[(1 * H + j) * H];
    const float* Wnp = &W_hh[(2 * H + j) * H];
    unsigned wr[16], wz[16], wn[16];
#pragma unroll
    for (int k = 0; k < 16; ++k) {
        wr[k] = pack2(Wrp[2 * k] * NL2E, Wrp[2 * k + 1] * NL2E);
        wz[k] = pack2(Wzp[2 * k] * NL2E, Wzp[2 * k + 1] * NL2E);
        wn[k] = pack2(Wnp[2 * k] * P2L2, Wnp[2 * k + 1] * P2L2);
    }
    const float wir = W_ih[j] * NL2E;
    const float wiz = W_ih[H + j] * NL2E;
    const float br  = (b_ih[j] + b_hh[j]) * NL2E;
    const float bz  = (b_ih[H + j] + b_hh[H + j]) * NL2E;
    const float bhn = b_hh[2 * H + j] * P2L2;
    const float win = W_ih[2 * H + j] * P2L2;
    const float bin = b_ih[2 * H + j] * P2L2;
    const float wo  = W_out[j];
    const float bo  = b_out[0];

    float h = h0[b * H + j];

    const float* xb = x + (size_t)b * TT;
    float*       yb = out + (size_t)b * TT;

    const unsigned ha = (unsigned)(size_t)&hbuf[w][half * 32 + j];   // publish
    const unsigned hr = (unsigned)(size_t)&hbuf[w][half * 32];       // 64B reads
    const unsigned xw = (unsigned)(size_t)&xstage[w][half][j];       // stage
    const unsigned xa = (unsigned)(size_t)&xstage[w][half][0];       // b64 reads
    const unsigned ya = (unsigned)(size_t)&ybuf[w][half][j];         // y stash
    const float* yr = &ybuf[w][half][0];

#pragma unroll 1
    for (int t0 = 0; t0 < TT; t0 += 32) {
        const float xv = xb[t0 + j];

        asm volatile(
            "s_mov_b32 s20, 16\n\t"
            "v_mov_b32 v82, %[ya]\n\t"
            "v_mov_b32 v83, %[xa]\n\t"
            // prologue DS order: [xwr, xrd, pub, r0-r3, ywrD] -- matches
            // the steady-state wait grading (after-r0 = 4 ops).
            "ds_write_b32 %[xw], %[xv]\n\t"
            "ds_read_b64 v[80:81], v83\n\t"            // x_0, x_1
            "v_cvt_f16_f32 v33, %[h]\n\t"
            "ds_write_b16 %[ha], v33\n\t"
            "ds_read_b128 v[36:39], %[hr]\n\t"
            "ds_read_b128 v[40:43], %[hr] offset:16\n\t"
            "ds_read_b128 v[44:47], %[hr] offset:32\n\t"
            "ds_read_b128 v[48:51], %[hr] offset:48\n\t"
            "ds_write_b32 v82, v78\n\t"                // dummy y (overwritten)

            "L_gru_%=:\n\t"
            // ---------- step A (even) ----------
            DOT48G
            TAILA
            // publish + reads for step B, then y-write A (after reads)
            "v_cvt_f16_f32 v33, %[h]\n\t"
            "ds_write_b16 %[ha], v33\n\t"
            "ds_read_b128 v[36:39], %[hr]\n\t"
            "ds_read_b128 v[40:43], %[hr] offset:16\n\t"
            "ds_read_b128 v[44:47], %[hr] offset:32\n\t"
            "ds_read_b128 v[48:51], %[hr] offset:48\n\t"
            "v_mul_f32 v78, %[wo], %[h]\n\t"
            "ds_write_b32 v82, v78\n\t"                // ywrA
            // ---------- step B (odd) ----------
            DOT48G
            TAILB                                       // x-prefetch + counter inside
            // publish + reads for next iter's step A
            "v_cvt_f16_f32 v33, %[h]\n\t"
            "ds_write_b16 %[ha], v33\n\t"
            "ds_read_b128 v[36:39], %[hr]\n\t"
            "ds_read_b128 v[40:43], %[hr] offset:16\n\t"
            "ds_read_b128 v[44:47], %[hr] offset:32\n\t"
            "ds_read_b128 v[48:51], %[hr] offset:48\n\t"
            "v_mul_f32 v78, %[wo], %[h]\n\t"
            "ds_write_b32 v82, v78 offset:132\n\t"     // ywrB
            "v_add_u32 v82, 264, v82\n\t"
            "s_cbranch_scc1 L_gru_%=\n\t"
            "s_waitcnt lgkmcnt(0)"
            : [h]"+v"(h)
            : [xv]"v"(xv), [ha]"v"(ha), [hr]"v"(hr), [xw]"v"(xw), [xa]"v"(xa),
              [ya]"v"(ya),
              [wir]"v"(wir), [wiz]"v"(wiz), [wi]"v"(win), [bi]"v"(bin),
              [wo]"v"(wo), [br]"v"(br), [bz]"v"(bz), [bn]"v"(bhn),
              [r0]"v"(wr[0]), [r1]"v"(wr[1]), [r2]"v"(wr[2]), [r3]"v"(wr[3]),
              [r4]"v"(wr[4]), [r5]"v"(wr[5]), [r6]"v"(wr[6]), [r7]"v"(wr[7]),
              [r8]"v"(wr[8]), [r9]"v"(wr[9]), [r10]"v"(wr[10]), [r11]"v"(wr[11]),
              [r12]"v"(wr[12]), [r13]"v"(wr[13]), [r14]"v"(wr[14]), [r15]"v"(wr[15]),
              [z0]"v"(wz[0]), [z1]"v"(wz[1]), [z2]"v"(wz[2]), [z3]"v"(wz[3]),
              [z4]"v"(wz[4]), [z5]"v"(wz[5]), [z6]"v"(wz[6]), [z7]"v"(wz[7]),
              [z8]"v"(wz[8]), [z9]"v"(wz[9]), [z10]"v"(wz[10]), [z11]"v"(wz[11]),
              [z12]"v"(wz[12]), [z13]"v"(wz[13]), [z14]"v"(wz[14]), [z15]"v"(wz[15]),
              [n0]"v"(wn[0]), [n1]"v"(wn[1]), [n2]"v"(wn[2]), [n3]"v"(wn[3]),
              [n4]"v"(wn[4]), [n5]"v"(wn[5]), [n6]"v"(wn[6]), [n7]"v"(wn[7]),
              [n8]"v"(wn[8]), [n9]"v"(wn[9]), [n10]"v"(wn[10]), [n11]"v"(wn[11]),
              [n12]"v"(wn[12]), [n13]"v"(wn[13]), [n14]"v"(wn[14]), [n15]"v"(wn[15])
            : "memory", "scc", "s20",
              "v33", "v36", "v37", "v38", "v39", "v40", "v41", "v42", "v43",
              "v44", "v45", "v46", "v47", "v48", "v49", "v50", "v51",
              "v68", "v69", "v70", "v71", "v72", "v74", "v75", "v76", "v77",
              "v78", "v80", "v81", "v82", "v83");

        // amortized y reduction: stride 33 (conflict-free across j)
        float s0 = 0.0f, s1 = 0.0f, s2 = 0.0f, s3 = 0.0f;
#pragma unroll
        for (int k = 0; k < 32; k += 4) {
            s0 += yr[33 * j + k + 0];
            s1 += yr[33 * j + k + 1];
            s2 += yr[33 * j + k + 2];
            s3 += yr[33 * j + k + 3];
        }
        yb[t0 + j] = (s0 + s1) + (s2 + s3) + bo;
        __builtin_amdgcn_wave_barrier();
    }

    out[(size_t)BB * TT + b * H + j] = h;

#undef DOT12_0
#undef DOT12_1
#undef DOT12_2
#undef DOT12_3
#undef DOT48G
#undef TAILA
#undef TAILB
}

extern "C" void kernel_launch(void* const* d_in, const int* in_sizes, int n_in,
                              void* d_out, int out_size, void* d_ws, size_t ws_size,
                              hipStream_t stream) {
    const float* x     = (const float*)d_in[0];
    const float* h0    = (const float*)d_in[1];
    const float* W_ih  = (const float*)d_in[2];
    const float* W_hh  = (const float*)d_in[3];
    const float* b_ih  = (const float*)d_in[4];
    const float* b_hh  = (const float*)d_in[5];
    const float* W_out = (const float*)d_in[6];
    const float* b_out = (const float*)d_in[7];
    float* out = (float*)d_out;

    dim3 grid(BB / 8);   // 256 blocks: 4 waves x 2 batches each = 1024 waves
    dim3 block(256);
    gru_fused<<<grid, block, 0, stream>>>(x, h0, W_ih, W_hh, b_ih, b_hh,
                                          W_out, b_out, out);
}